// Round 14
// baseline (405.996 us; speedup 1.0000x reference)
//
#include <hip/hip_runtime.h>
#include <hip/hip_fp16.h>
#include <math.h>

#define N_NODES 262144
#define N_EDGES 4194304
#define N_GRAPHS 1024
#define NBK 512                  // dst buckets (512 nodes each)
#define CAP 8960                 // per-bucket capacity (mean 8192 + 8.5 sigma)
#define ABLK 512                 // fusedAB blocks
#define AEPB (N_EDGES / ABLK)    // 8192 edges per block; run = 16 edges = 64B

typedef _Float16 half2v __attribute__((ext_vector_type(2)));
typedef int int4v __attribute__((ext_vector_type(4)));
__device__ inline half2v u2h(unsigned u) { union { unsigned u; half2v h; } c; c.u = u; return c.h; }
__device__ inline unsigned packh2(float a, float b) {
    union { __half2 h; unsigned u; } c; c.h = __floats2half2_rn(a, b); return c.u;
}

// ---------------------------------------------------------------------------
// fusedAB: pack px16 + zero pooled + per-block bucket hist (int4 nt reads) +
// global range reservation + line-dense binned scatter (nt stores).
// All ei traffic is single-use -> nontemporal, keeps L2 free for px16.
// ---------------------------------------------------------------------------
__global__ __launch_bounds__(256) void fusedAB(
    const int* __restrict__ ei, const float* __restrict__ x,
    const float* __restrict__ pos, int* __restrict__ gcur,
    int* __restrict__ binned, uint4* __restrict__ px16,
    float* __restrict__ pooled)
{
    __shared__ int lh[NBK];
    int t = threadIdx.x, b = blockIdx.x;

    // pack 2 nodes per thread (fp16 x4 + pos3 -> one 16B record, 4MB total)
    #pragma unroll
    for (int k = 0; k < 2; ++k) {
        int n = b * 512 + k * 256 + t;
        float4 v = ((const float4*)x)[n];
        float p0 = pos[3 * n], p1 = pos[3 * n + 1], p2 = pos[3 * n + 2];
        uint4 r;
        r.x = packh2(v.x, v.y);
        r.y = packh2(v.z, v.w);
        r.z = packh2(p0, p1);
        r.w = packh2(p2, 0.0f);
        px16[n] = r;
    }
    int pid = b * 256 + t;
    if (pid < 1025 * 32) pooled[pid] = 0.0f;

    #pragma unroll
    for (int k = 0; k < 2; ++k) lh[t + 256 * k] = 0;
    __syncthreads();

    const int4v* dsts = (const int4v*)(ei + N_EDGES + b * AEPB);
    #pragma unroll
    for (int i = 0; i < AEPB / 1024; ++i) {
        int4v d4 = __builtin_nontemporal_load(dsts + i * 256 + t);
        atomicAdd(&lh[d4.x >> 9], 1);
        atomicAdd(&lh[d4.y >> 9], 1);
        atomicAdd(&lh[d4.z >> 9], 1);
        atomicAdd(&lh[d4.w >> 9], 1);
    }
    __syncthreads();
    #pragma unroll
    for (int k = 0; k < 2; ++k) {
        int kb = t + 256 * k;
        lh[kb] = atomicAdd(&gcur[kb * 16], lh[kb]);   // reserve contiguous range
    }
    __syncthreads();
    int base = b * AEPB;
    for (int i = 0; i < AEPB / 256; ++i) {
        int e = base + i * 256 + t;
        int s = __builtin_nontemporal_load(ei + e);
        int d = __builtin_nontemporal_load(ei + N_EDGES + e);
        int slot = atomicAdd(&lh[d >> 9], 1);
        if (slot < CAP)
            __builtin_nontemporal_store(s | ((d & 511) << 18),
                                        binned + (size_t)(d >> 9) * CAP + slot);
    }
}

// ---------------------------------------------------------------------------
// passC: per-bucket counting sort of nodes by degree -> perm, then in-place
// rewrite of binned into PERM-ORDERED node-grouped src lists (nt load/store).
// ---------------------------------------------------------------------------
__global__ __launch_bounds__(512) void passC_sort(
    const int* __restrict__ gcur,
    int* __restrict__ binned,
    int* __restrict__ startg, int* __restrict__ degg,
    int* __restrict__ perm)
{
    __shared__ int lbuf[CAP];
    __shared__ int ldeg[512], rdeg[512], lcur[512];
    __shared__ int dh[64];
    int t = threadIdx.x, k = blockIdx.x;
    int ebase = k * CAP;
    int cnt = gcur[k * 16];
    if (cnt > CAP) cnt = CAP;

    ldeg[t] = 0;
    if (t < 64) dh[t] = 0;
    __syncthreads();
    for (int i = t; i < cnt; i += 512) {
        int pk = __builtin_nontemporal_load(binned + ebase + i);
        lbuf[i] = pk;
        atomicAdd(&ldeg[pk >> 18], 1);
    }
    __syncthreads();
    int dgv = ldeg[t];
    int bin = dgv < 63 ? dgv : 63;
    atomicAdd(&dh[bin], 1);
    __syncthreads();
    if (t == 0) {   // serial 64-bin exclusive scan (once per block)
        int acc = 0;
        #pragma unroll
        for (int i = 0; i < 64; ++i) { int c = dh[i]; dh[i] = acc; acc += c; }
    }
    __syncthreads();
    int r = atomicAdd(&dh[bin], 1);      // deg-sorted rank of this node
    int n = k * 512 + t;
    perm[(k << 9) + r] = n;
    rdeg[r] = dgv;
    __syncthreads();
    // Hillis-Steele inclusive scan over rank-ordered degrees (reuse ldeg)
    ldeg[t] = rdeg[t];
    __syncthreads();
    for (int o = 1; o < 512; o <<= 1) {
        int u = (t >= o) ? ldeg[t - o] : 0;
        __syncthreads();
        ldeg[t] += u;
        __syncthreads();
    }
    int excl = ldeg[r] - rdeg[r];        // perm-order offset for this node
    startg[n] = ebase + excl;
    degg[n] = dgv;
    lcur[t] = excl;
    __syncthreads();
    for (int i = t; i < cnt; i += 512) {
        int pk = lbuf[i];
        int sl = atomicAdd(&lcur[pk >> 18], 1);
        __builtin_nontemporal_store(pk & 0x3FFFF, binned + ebase + sl);
    }
}

// ---------------------------------------------------------------------------
// Gather + edge MLP (R7-verified inner loop). Deg-sorted perm order, CSR in
// perm order (sequential srcs). All single-use streams nontemporal so the
// 4MB px16 table stays L2-resident (16x reuse). Pooling over <=8 graph rows.
// ---------------------------------------------------------------------------
__global__ __launch_bounds__(256) void node_gather_fused(
    const uint4* __restrict__ px16,
    const int* __restrict__ srcs, const int* __restrict__ startg,
    const int* __restrict__ degg, const int* __restrict__ perm,
    const float* __restrict__ W1, const float* __restrict__ b1,
    const float* __restrict__ W2, const float* __restrict__ b2,
    const float* __restrict__ Wp, const float* __restrict__ bp,
    const int* __restrict__ batch,
    float* __restrict__ out_s, float* __restrict__ pooled)
{
    __shared__ uint4 sepk[16][17];   // staged edges: {x01,x23,dist,pad}
    __shared__ float smh[16][20];    // sumH transpose (padded rows)
    __shared__ float lpool[8][33];
    __shared__ int sg0;

    int t = threadIdx.x;
    int g = t & 15;
    int grp = t >> 4;
    int n = __builtin_nontemporal_load(perm + blockIdx.x * 16 + grp);

    // per-lane weights (registers)
    float w1c0 = W1[0 * 16 + g], w1c1 = W1[1 * 16 + g];
    float w1c2 = W1[2 * 16 + g], w1c3 = W1[3 * 16 + g];
    half2v wh45, wh67;
    wh45[0] = (_Float16)W1[4 * 16 + g];
    wh45[1] = (_Float16)W1[5 * 16 + g];
    wh67[0] = (_Float16)W1[6 * 16 + g];
    wh67[1] = (_Float16)W1[7 * 16 + g];
    float w1c8 = W1[8 * 16 + g];
    float b1g = b1[g], b2g = b2[g];
    float w2col[16];
    #pragma unroll
    for (int i = 0; i < 16; ++i) w2col[i] = W2[i * 16 + g];  // column g
    float wp0 = Wp[2 * g], wp1 = Wp[2 * g + 1];

    int base = __builtin_nontemporal_load(startg + n);
    int dg = __builtin_nontemporal_load(degg + n);

    // self record (keep cached: px16 is the reuse-heavy table)
    uint4 rn = px16[n];
    float2 f01 = __half22float2(*(__half2*)&rn.x);
    float2 f23 = __half22float2(*(__half2*)&rn.y);
    float2 f45 = __half22float2(*(__half2*)&rn.z);
    float2 f67 = __half22float2(*(__half2*)&rn.w);
    float pnx = f45.x, pny = f45.y, pnz = f67.x;
    float pre = b1g + f01.x * w1c0 + f01.y * w1c1 + f23.x * w1c2 + f23.y * w1c3;

    float sumH = 0.0f;

    // pipeline prologue
    int sC = 0;
    if (g < dg) sC = __builtin_nontemporal_load(srcs + base + g);
    uint4 rC = px16[sC];
    int sN = sC;
    if (16 + g < dg) sN = __builtin_nontemporal_load(srcs + base + 16 + g);

    for (int k0 = 0; k0 < dg; k0 += 16) {
        int rem = dg - k0;
        int cnt = rem < 16 ? rem : 16;
        if (g < cnt) {
            float2 e45 = __half22float2(*(__half2*)&rC.z);
            float2 e67 = __half22float2(*(__half2*)&rC.w);
            float dx = e45.x - pnx, dy = e45.y - pny, dz = e67.x - pnz;
            float dist = sqrtf(dx * dx + dy * dy + dz * dz);
            sepk[grp][g] = make_uint4(rC.x, rC.y, __float_as_uint(dist), 0u);
        }
        // issue next chunk's loads
        uint4 rNext = px16[sN];
        int sNN = sN;
        if (k0 + 32 + g < dg) sNN = __builtin_nontemporal_load(srcs + base + k0 + 32 + g);
        // compute current chunk from LDS (2x unrolled to batch waits)
        int j = 0;
        for (; j + 1 < cnt; j += 2) {
            uint4 A = sepk[grp][j];
            uint4 B = sepk[grp][j + 1];
            float a = fmaf(__uint_as_float(A.z), w1c8, pre);
            a = __builtin_amdgcn_fdot2(u2h(A.x), wh45, a, false);
            a = __builtin_amdgcn_fdot2(u2h(A.y), wh67, a, false);
            sumH += a * __builtin_amdgcn_rcpf(1.0f + __expf(-a));
            float b = fmaf(__uint_as_float(B.z), w1c8, pre);
            b = __builtin_amdgcn_fdot2(u2h(B.x), wh45, b, false);
            b = __builtin_amdgcn_fdot2(u2h(B.y), wh67, b, false);
            sumH += b * __builtin_amdgcn_rcpf(1.0f + __expf(-b));
        }
        if (j < cnt) {
            uint4 A = sepk[grp][j];
            float a = fmaf(__uint_as_float(A.z), w1c8, pre);
            a = __builtin_amdgcn_fdot2(u2h(A.x), wh45, a, false);
            a = __builtin_amdgcn_fdot2(u2h(A.y), wh67, a, false);
            sumH += a * __builtin_amdgcn_rcpf(1.0f + __expf(-a));
        }
        rC = rNext;
        sN = sNN;
    }

    // LDS-transpose epilogue: lane g applies W2 column g.
    smh[grp][g] = sumH;
    float4 s0v = *(const float4*)&smh[grp][0];
    float4 s1v = *(const float4*)&smh[grp][4];
    float4 s2v = *(const float4*)&smh[grp][8];
    float4 s3v = *(const float4*)&smh[grp][12];
    float red = s0v.x * w2col[0] + s0v.y * w2col[1] + s0v.z * w2col[2] + s0v.w * w2col[3]
              + s1v.x * w2col[4] + s1v.y * w2col[5] + s1v.z * w2col[6] + s1v.w * w2col[7]
              + s2v.x * w2col[8] + s2v.y * w2col[9] + s2v.z * w2col[10] + s2v.w * w2col[11]
              + s3v.x * w2col[12] + s3v.y * w2col[13] + s3v.z * w2col[14] + s3v.w * w2col[15];

    float fdg = (float)dg;
    float inv = 1.0f / fmaxf(fdg, 1.0f);
    float h = fmaxf((red + fdg * b2g) * inv, 0.0f);

    // logits via 16-lane allreduce
    float c0 = h * wp0, c1 = h * wp1;
    #pragma unroll
    for (int mset = 8; mset > 0; mset >>= 1) {
        c0 += __shfl_xor(c0, mset);
        c1 += __shfl_xor(c1, mset);
    }
    float l0 = c0 + bp[0], l1 = c1 + bp[1];
    float mx = fmaxf(l0, l1);
    float e0s = __expf(l0 - mx), e1s = __expf(l1 - mx);
    float isum = 1.0f / (e0s + e1s);
    float s0 = e0s * isum, s1 = e1s * isum;

    if (g == 0) {
        __builtin_nontemporal_store(s0, out_s + 2 * n);
        __builtin_nontemporal_store(s1, out_s + 2 * n + 1);
    }

    // pooling: block nodes span <=8 graphs of the bucket (bucket = blk>>5)
    if (t == 0) sg0 = batch[(blockIdx.x >> 5) << 9];
    lpool[t >> 5][t & 31] = 0.0f;
    __syncthreads();

    int gid = batch[n];
    int idx = gid - sg0;
    float p0 = s0 * h, p1 = s1 * h;
    if (idx < 8) {
        atomicAdd(&lpool[idx][g], p0);
        atomicAdd(&lpool[idx][16 + g], p1);
    } else {  // pathological tiny-graph fallback
        atomicAdd(&pooled[gid * 32 + g], p0);
        atomicAdd(&pooled[gid * 32 + 16 + g], p1);
    }
    __syncthreads();
    float v = lpool[t >> 5][t & 31];
    if (v != 0.0f) atomicAdd(&pooled[(sg0 + (t >> 5)) * 32 + (t & 31)], v);
}

// ---------------------------------------------------------------------------
// z = pooled.reshape(G,32) @ Wz + bz
// ---------------------------------------------------------------------------
__global__ __launch_bounds__(256) void z_kernel(const float* __restrict__ pooled,
                                                const float* __restrict__ Wz,
                                                const float* __restrict__ bz,
                                                float* __restrict__ out_z) {
    int idx = blockIdx.x * 256 + threadIdx.x;
    if (idx >= N_GRAPHS * 8) return;
    int gph = idx >> 3, o = idx & 7;
    float a = bz[o];
    const float* pp = pooled + (size_t)gph * 32;
    #pragma unroll
    for (int j = 0; j < 32; ++j) a = fmaf(pp[j], Wz[j * 8 + o], a);
    out_z[idx] = a;
}

extern "C" void kernel_launch(void* const* d_in, const int* in_sizes, int n_in,
                              void* d_out, int out_size, void* d_ws, size_t ws_size,
                              hipStream_t stream) {
    const float* x    = (const float*)d_in[0];
    const float* pos  = (const float*)d_in[1];
    const float* W1   = (const float*)d_in[2];
    const float* b1   = (const float*)d_in[3];
    const float* W2   = (const float*)d_in[4];
    const float* b2   = (const float*)d_in[5];
    const float* Wp   = (const float*)d_in[6];
    const float* bp   = (const float*)d_in[7];
    const float* Wz   = (const float*)d_in[8];
    const float* bz   = (const float*)d_in[9];
    const int*   ei   = (const int*)d_in[10];
    const int*   batch= (const int*)d_in[11];
    float* out = (float*)d_out;
    float* out_z = out;                   // [1024*8]
    float* out_s = out + N_GRAPHS * 8;    // [262144*2]

    // ws (ints): gcur[NBK*16] | binned[NBK*CAP] (=srcs after passC) |
    //            startg[N] | degg[N] | perm[N] | pooled[1025*32] | px16[N uint4]
    int* gcur     = (int*)d_ws;
    int* binned   = gcur + NBK * 16;
    int* startg   = binned + (size_t)NBK * CAP;
    int* degg     = startg + N_NODES;
    int* perm     = degg + N_NODES;
    float* pooled = (float*)(perm + N_NODES);
    uint4* px16   = (uint4*)(pooled + 1025 * 32);   // offset is 16B-aligned

    hipMemsetAsync(gcur, 0, NBK * 16 * sizeof(int), stream);
    fusedAB<<<ABLK, 256, 0, stream>>>(ei, x, pos, gcur, binned, px16, pooled);
    passC_sort<<<NBK, 512, 0, stream>>>(gcur, binned, startg, degg, perm);
    node_gather_fused<<<N_NODES / 16, 256, 0, stream>>>(
        px16, binned, startg, degg, perm, W1, b1, W2, b2, Wp, bp, batch, out_s, pooled);
    z_kernel<<<32, 256, 0, stream>>>(pooled, Wz, bz, out_z);
}

// Round 15
// 230.513 us; speedup vs baseline: 1.7613x; 1.7613x over previous
//
#include <hip/hip_runtime.h>
#include <hip/hip_fp16.h>
#include <math.h>

#define N_NODES 262144
#define N_EDGES 4194304
#define N_GRAPHS 1024
#define NBK 512                  // dst buckets (512 nodes each)
#define CAP 8960                 // per-bucket capacity (mean 8192 + 8.5 sigma)
#define ABLK 512                 // fusedAB blocks
#define AEPB (N_EDGES / ABLK)    // 8192 edges per block; run = 16 edges = 64B

typedef _Float16 half2v __attribute__((ext_vector_type(2)));
typedef int int4v __attribute__((ext_vector_type(4)));
__device__ inline half2v u2h(unsigned u) { union { unsigned u; half2v h; } c; c.u = u; return c.h; }
__device__ inline unsigned packh2(float a, float b) {
    union { __half2 h; unsigned u; } c; c.h = __floats2half2_rn(a, b); return c.u;
}

// ---------------------------------------------------------------------------
// fusedAB: pack px16 + zero pooled + per-block bucket hist (int4 nt reads) +
// global range reservation + line-dense binned scatter (CACHED stores: L2
// write-coalescing is what makes the 16-edge runs line-dense; nt stores
// write through as partial lines and cost 6x — measured R14).
// ---------------------------------------------------------------------------
__global__ __launch_bounds__(256) void fusedAB(
    const int* __restrict__ ei, const float* __restrict__ x,
    const float* __restrict__ pos, int* __restrict__ gcur,
    int* __restrict__ binned, uint4* __restrict__ px16,
    float* __restrict__ pooled)
{
    __shared__ int lh[NBK];
    int t = threadIdx.x, b = blockIdx.x;

    // pack 2 nodes per thread (fp16 x4 + pos3 -> one 16B record, 4MB total)
    #pragma unroll
    for (int k = 0; k < 2; ++k) {
        int n = b * 512 + k * 256 + t;
        float4 v = ((const float4*)x)[n];
        float p0 = pos[3 * n], p1 = pos[3 * n + 1], p2 = pos[3 * n + 2];
        uint4 r;
        r.x = packh2(v.x, v.y);
        r.y = packh2(v.z, v.w);
        r.z = packh2(p0, p1);
        r.w = packh2(p2, 0.0f);
        px16[n] = r;
    }
    int pid = b * 256 + t;
    if (pid < 1025 * 32) pooled[pid] = 0.0f;

    #pragma unroll
    for (int k = 0; k < 2; ++k) lh[t + 256 * k] = 0;
    __syncthreads();

    const int4v* dsts = (const int4v*)(ei + N_EDGES + b * AEPB);
    #pragma unroll
    for (int i = 0; i < AEPB / 1024; ++i) {
        int4v d4 = __builtin_nontemporal_load(dsts + i * 256 + t);
        atomicAdd(&lh[d4.x >> 9], 1);
        atomicAdd(&lh[d4.y >> 9], 1);
        atomicAdd(&lh[d4.z >> 9], 1);
        atomicAdd(&lh[d4.w >> 9], 1);
    }
    __syncthreads();
    #pragma unroll
    for (int k = 0; k < 2; ++k) {
        int kb = t + 256 * k;
        lh[kb] = atomicAdd(&gcur[kb * 16], lh[kb]);   // reserve contiguous range
    }
    __syncthreads();
    int base = b * AEPB;
    for (int i = 0; i < AEPB / 256; ++i) {
        int e = base + i * 256 + t;
        int s = __builtin_nontemporal_load(ei + e);
        int d = __builtin_nontemporal_load(ei + N_EDGES + e);
        int slot = atomicAdd(&lh[d >> 9], 1);
        if (slot < CAP)
            binned[(size_t)(d >> 9) * CAP + slot] = s | ((d & 511) << 18);
    }
}

// ---------------------------------------------------------------------------
// passC: per-bucket counting sort of nodes by degree -> perm, then in-place
// rewrite of binned into PERM-ORDERED node-grouped src lists (nt loads,
// cached stores).
// ---------------------------------------------------------------------------
__global__ __launch_bounds__(512) void passC_sort(
    const int* __restrict__ gcur,
    int* __restrict__ binned,
    int* __restrict__ startg, int* __restrict__ degg,
    int* __restrict__ perm)
{
    __shared__ int lbuf[CAP];
    __shared__ int ldeg[512], rdeg[512], lcur[512];
    __shared__ int dh[64];
    int t = threadIdx.x, k = blockIdx.x;
    int ebase = k * CAP;
    int cnt = gcur[k * 16];
    if (cnt > CAP) cnt = CAP;

    ldeg[t] = 0;
    if (t < 64) dh[t] = 0;
    __syncthreads();
    for (int i = t; i < cnt; i += 512) {
        int pk = __builtin_nontemporal_load(binned + ebase + i);
        lbuf[i] = pk;
        atomicAdd(&ldeg[pk >> 18], 1);
    }
    __syncthreads();
    int dgv = ldeg[t];
    int bin = dgv < 63 ? dgv : 63;
    atomicAdd(&dh[bin], 1);
    __syncthreads();
    if (t == 0) {   // serial 64-bin exclusive scan (once per block)
        int acc = 0;
        #pragma unroll
        for (int i = 0; i < 64; ++i) { int c = dh[i]; dh[i] = acc; acc += c; }
    }
    __syncthreads();
    int r = atomicAdd(&dh[bin], 1);      // deg-sorted rank of this node
    int n = k * 512 + t;
    perm[(k << 9) + r] = n;
    rdeg[r] = dgv;
    __syncthreads();
    // Hillis-Steele inclusive scan over rank-ordered degrees (reuse ldeg)
    ldeg[t] = rdeg[t];
    __syncthreads();
    for (int o = 1; o < 512; o <<= 1) {
        int u = (t >= o) ? ldeg[t - o] : 0;
        __syncthreads();
        ldeg[t] += u;
        __syncthreads();
    }
    int excl = ldeg[r] - rdeg[r];        // perm-order offset for this node
    startg[n] = ebase + excl;
    degg[n] = dgv;
    lcur[t] = excl;
    __syncthreads();
    for (int i = t; i < cnt; i += 512) {
        int pk = lbuf[i];
        int sl = atomicAdd(&lcur[pk >> 18], 1);
        binned[ebase + sl] = pk & 0x3FFFF;
    }
}

// ---------------------------------------------------------------------------
// Gather + edge MLP (R7-verified inner loop). Deg-sorted perm order, CSR in
// perm order (sequential srcs, nt loads). px16 stays L2-cached (16x reuse).
// Pooling over <=8 graph rows per block.
// ---------------------------------------------------------------------------
__global__ __launch_bounds__(256) void node_gather_fused(
    const uint4* __restrict__ px16,
    const int* __restrict__ srcs, const int* __restrict__ startg,
    const int* __restrict__ degg, const int* __restrict__ perm,
    const float* __restrict__ W1, const float* __restrict__ b1,
    const float* __restrict__ W2, const float* __restrict__ b2,
    const float* __restrict__ Wp, const float* __restrict__ bp,
    const int* __restrict__ batch,
    float* __restrict__ out_s, float* __restrict__ pooled)
{
    __shared__ uint4 sepk[16][17];   // staged edges: {x01,x23,dist,pad}
    __shared__ float smh[16][20];    // sumH transpose (padded rows)
    __shared__ float lpool[8][33];
    __shared__ int sg0;

    int t = threadIdx.x;
    int g = t & 15;
    int grp = t >> 4;
    int n = __builtin_nontemporal_load(perm + blockIdx.x * 16 + grp);

    // per-lane weights (registers)
    float w1c0 = W1[0 * 16 + g], w1c1 = W1[1 * 16 + g];
    float w1c2 = W1[2 * 16 + g], w1c3 = W1[3 * 16 + g];
    half2v wh45, wh67;
    wh45[0] = (_Float16)W1[4 * 16 + g];
    wh45[1] = (_Float16)W1[5 * 16 + g];
    wh67[0] = (_Float16)W1[6 * 16 + g];
    wh67[1] = (_Float16)W1[7 * 16 + g];
    float w1c8 = W1[8 * 16 + g];
    float b1g = b1[g], b2g = b2[g];
    float w2col[16];
    #pragma unroll
    for (int i = 0; i < 16; ++i) w2col[i] = W2[i * 16 + g];  // column g
    float wp0 = Wp[2 * g], wp1 = Wp[2 * g + 1];

    int base = __builtin_nontemporal_load(startg + n);
    int dg = __builtin_nontemporal_load(degg + n);

    // self record (keep cached: px16 is the reuse-heavy table)
    uint4 rn = px16[n];
    float2 f01 = __half22float2(*(__half2*)&rn.x);
    float2 f23 = __half22float2(*(__half2*)&rn.y);
    float2 f45 = __half22float2(*(__half2*)&rn.z);
    float2 f67 = __half22float2(*(__half2*)&rn.w);
    float pnx = f45.x, pny = f45.y, pnz = f67.x;
    float pre = b1g + f01.x * w1c0 + f01.y * w1c1 + f23.x * w1c2 + f23.y * w1c3;

    float sumH = 0.0f;

    // pipeline prologue
    int sC = 0;
    if (g < dg) sC = __builtin_nontemporal_load(srcs + base + g);
    uint4 rC = px16[sC];
    int sN = sC;
    if (16 + g < dg) sN = __builtin_nontemporal_load(srcs + base + 16 + g);

    for (int k0 = 0; k0 < dg; k0 += 16) {
        int rem = dg - k0;
        int cnt = rem < 16 ? rem : 16;
        if (g < cnt) {
            float2 e45 = __half22float2(*(__half2*)&rC.z);
            float2 e67 = __half22float2(*(__half2*)&rC.w);
            float dx = e45.x - pnx, dy = e45.y - pny, dz = e67.x - pnz;
            float dist = sqrtf(dx * dx + dy * dy + dz * dz);
            sepk[grp][g] = make_uint4(rC.x, rC.y, __float_as_uint(dist), 0u);
        }
        // issue next chunk's loads
        uint4 rNext = px16[sN];
        int sNN = sN;
        if (k0 + 32 + g < dg) sNN = __builtin_nontemporal_load(srcs + base + k0 + 32 + g);
        // compute current chunk from LDS (2x unrolled to batch waits)
        int j = 0;
        for (; j + 1 < cnt; j += 2) {
            uint4 A = sepk[grp][j];
            uint4 B = sepk[grp][j + 1];
            float a = fmaf(__uint_as_float(A.z), w1c8, pre);
            a = __builtin_amdgcn_fdot2(u2h(A.x), wh45, a, false);
            a = __builtin_amdgcn_fdot2(u2h(A.y), wh67, a, false);
            sumH += a * __builtin_amdgcn_rcpf(1.0f + __expf(-a));
            float b = fmaf(__uint_as_float(B.z), w1c8, pre);
            b = __builtin_amdgcn_fdot2(u2h(B.x), wh45, b, false);
            b = __builtin_amdgcn_fdot2(u2h(B.y), wh67, b, false);
            sumH += b * __builtin_amdgcn_rcpf(1.0f + __expf(-b));
        }
        if (j < cnt) {
            uint4 A = sepk[grp][j];
            float a = fmaf(__uint_as_float(A.z), w1c8, pre);
            a = __builtin_amdgcn_fdot2(u2h(A.x), wh45, a, false);
            a = __builtin_amdgcn_fdot2(u2h(A.y), wh67, a, false);
            sumH += a * __builtin_amdgcn_rcpf(1.0f + __expf(-a));
        }
        rC = rNext;
        sN = sNN;
    }

    // LDS-transpose epilogue: lane g applies W2 column g.
    smh[grp][g] = sumH;
    float4 s0v = *(const float4*)&smh[grp][0];
    float4 s1v = *(const float4*)&smh[grp][4];
    float4 s2v = *(const float4*)&smh[grp][8];
    float4 s3v = *(const float4*)&smh[grp][12];
    float red = s0v.x * w2col[0] + s0v.y * w2col[1] + s0v.z * w2col[2] + s0v.w * w2col[3]
              + s1v.x * w2col[4] + s1v.y * w2col[5] + s1v.z * w2col[6] + s1v.w * w2col[7]
              + s2v.x * w2col[8] + s2v.y * w2col[9] + s2v.z * w2col[10] + s2v.w * w2col[11]
              + s3v.x * w2col[12] + s3v.y * w2col[13] + s3v.z * w2col[14] + s3v.w * w2col[15];

    float fdg = (float)dg;
    float inv = 1.0f / fmaxf(fdg, 1.0f);
    float h = fmaxf((red + fdg * b2g) * inv, 0.0f);

    // logits via 16-lane allreduce
    float c0 = h * wp0, c1 = h * wp1;
    #pragma unroll
    for (int mset = 8; mset > 0; mset >>= 1) {
        c0 += __shfl_xor(c0, mset);
        c1 += __shfl_xor(c1, mset);
    }
    float l0 = c0 + bp[0], l1 = c1 + bp[1];
    float mx = fmaxf(l0, l1);
    float e0s = __expf(l0 - mx), e1s = __expf(l1 - mx);
    float isum = 1.0f / (e0s + e1s);
    float s0 = e0s * isum, s1 = e1s * isum;

    if (g == 0) ((float2*)out_s)[n] = make_float2(s0, s1);

    // pooling: block nodes span <=8 graphs of the bucket (bucket = blk>>5)
    if (t == 0) sg0 = batch[(blockIdx.x >> 5) << 9];
    lpool[t >> 5][t & 31] = 0.0f;
    __syncthreads();

    int gid = batch[n];
    int idx = gid - sg0;
    float p0 = s0 * h, p1 = s1 * h;
    if (idx < 8) {
        atomicAdd(&lpool[idx][g], p0);
        atomicAdd(&lpool[idx][16 + g], p1);
    } else {  // pathological tiny-graph fallback
        atomicAdd(&pooled[gid * 32 + g], p0);
        atomicAdd(&pooled[gid * 32 + 16 + g], p1);
    }
    __syncthreads();
    float v = lpool[t >> 5][t & 31];
    if (v != 0.0f) atomicAdd(&pooled[(sg0 + (t >> 5)) * 32 + (t & 31)], v);
}

// ---------------------------------------------------------------------------
// z = pooled.reshape(G,32) @ Wz + bz
// ---------------------------------------------------------------------------
__global__ __launch_bounds__(256) void z_kernel(const float* __restrict__ pooled,
                                                const float* __restrict__ Wz,
                                                const float* __restrict__ bz,
                                                float* __restrict__ out_z) {
    int idx = blockIdx.x * 256 + threadIdx.x;
    if (idx >= N_GRAPHS * 8) return;
    int gph = idx >> 3, o = idx & 7;
    float a = bz[o];
    const float* pp = pooled + (size_t)gph * 32;
    #pragma unroll
    for (int j = 0; j < 32; ++j) a = fmaf(pp[j], Wz[j * 8 + o], a);
    out_z[idx] = a;
}

extern "C" void kernel_launch(void* const* d_in, const int* in_sizes, int n_in,
                              void* d_out, int out_size, void* d_ws, size_t ws_size,
                              hipStream_t stream) {
    const float* x    = (const float*)d_in[0];
    const float* pos  = (const float*)d_in[1];
    const float* W1   = (const float*)d_in[2];
    const float* b1   = (const float*)d_in[3];
    const float* W2   = (const float*)d_in[4];
    const float* b2   = (const float*)d_in[5];
    const float* Wp   = (const float*)d_in[6];
    const float* bp   = (const float*)d_in[7];
    const float* Wz   = (const float*)d_in[8];
    const float* bz   = (const float*)d_in[9];
    const int*   ei   = (const int*)d_in[10];
    const int*   batch= (const int*)d_in[11];
    float* out = (float*)d_out;
    float* out_z = out;                   // [1024*8]
    float* out_s = out + N_GRAPHS * 8;    // [262144*2]

    // ws (ints): gcur[NBK*16] | binned[NBK*CAP] (=srcs after passC) |
    //            startg[N] | degg[N] | perm[N] | pooled[1025*32] | px16[N uint4]
    int* gcur     = (int*)d_ws;
    int* binned   = gcur + NBK * 16;
    int* startg   = binned + (size_t)NBK * CAP;
    int* degg     = startg + N_NODES;
    int* perm     = degg + N_NODES;
    float* pooled = (float*)(perm + N_NODES);
    uint4* px16   = (uint4*)(pooled + 1025 * 32);   // offset is 16B-aligned

    hipMemsetAsync(gcur, 0, NBK * 16 * sizeof(int), stream);
    fusedAB<<<ABLK, 256, 0, stream>>>(ei, x, pos, gcur, binned, px16, pooled);
    passC_sort<<<NBK, 512, 0, stream>>>(gcur, binned, startg, degg, perm);
    node_gather_fused<<<N_NODES / 16, 256, 0, stream>>>(
        px16, binned, startg, degg, perm, W1, b1, W2, b2, Wp, bp, batch, out_s, pooled);
    z_kernel<<<32, 256, 0, stream>>>(pooled, Wz, bz, out_z);
}

// Round 16
// 175.861 us; speedup vs baseline: 2.3086x; 1.3108x over previous
//
#include <hip/hip_runtime.h>
#include <hip/hip_fp16.h>
#include <math.h>

#define N_NODES 262144
#define N_EDGES 4194304
#define N_GRAPHS 1024
#define NBK 512                  // dst buckets (512 nodes each)
#define CAP 8960                 // per-bucket capacity (mean 8192 + 8.5 sigma)
#define ABLK 512                 // fusedAB blocks
#define AEPB (N_EDGES / ABLK)    // 8192 edges per block; run = 16 edges = 64B

typedef _Float16 half2v __attribute__((ext_vector_type(2)));
__device__ inline half2v u2h(unsigned u) { union { unsigned u; half2v h; } c; c.u = u; return c.h; }
__device__ inline unsigned packh2(float a, float b) {
    union { __half2 h; unsigned u; } c; c.h = __floats2half2_rn(a, b); return c.u;
}

// ---------------------------------------------------------------------------
// fusedAB (R10-verified): pack px16 + zero pooled + per-block bucket hist +
// global range reservation + line-dense binned scatter. All plain loads:
// nt hints measured net-negative (R14 stores 6x, R15 loads broke L2 reuse).
// ---------------------------------------------------------------------------
__global__ __launch_bounds__(256) void fusedAB(
    const int* __restrict__ ei, const float* __restrict__ x,
    const float* __restrict__ pos, int* __restrict__ gcur,
    int* __restrict__ binned, uint4* __restrict__ px16,
    float* __restrict__ pooled)
{
    __shared__ int lh[NBK];
    int t = threadIdx.x, b = blockIdx.x;

    // pack 2 nodes per thread (fp16 x4 + pos3 -> one 16B record, 4MB total)
    #pragma unroll
    for (int k = 0; k < 2; ++k) {
        int n = b * 512 + k * 256 + t;
        float4 v = ((const float4*)x)[n];
        float p0 = pos[3 * n], p1 = pos[3 * n + 1], p2 = pos[3 * n + 2];
        uint4 r;
        r.x = packh2(v.x, v.y);
        r.y = packh2(v.z, v.w);
        r.z = packh2(p0, p1);
        r.w = packh2(p2, 0.0f);
        px16[n] = r;
    }
    int pid = b * 256 + t;
    if (pid < 1025 * 32) pooled[pid] = 0.0f;

    #pragma unroll
    for (int k = 0; k < 2; ++k) lh[t + 256 * k] = 0;
    __syncthreads();

    const int4* dsts = (const int4*)(ei + N_EDGES + b * AEPB);
    #pragma unroll
    for (int i = 0; i < AEPB / 1024; ++i) {
        int4 d4 = dsts[i * 256 + t];
        atomicAdd(&lh[d4.x >> 9], 1);
        atomicAdd(&lh[d4.y >> 9], 1);
        atomicAdd(&lh[d4.z >> 9], 1);
        atomicAdd(&lh[d4.w >> 9], 1);
    }
    __syncthreads();
    #pragma unroll
    for (int k = 0; k < 2; ++k) {
        int kb = t + 256 * k;
        lh[kb] = atomicAdd(&gcur[kb * 16], lh[kb]);   // reserve contiguous range
    }
    __syncthreads();
    int base = b * AEPB;
    for (int i = 0; i < AEPB / 256; ++i) {
        int e = base + i * 256 + t;
        int s = ei[e];
        int d = ei[N_EDGES + e];
        int slot = atomicAdd(&lh[d >> 9], 1);
        if (slot < CAP)
            binned[(size_t)(d >> 9) * CAP + slot] = s | ((d & 511) << 18);
    }
}

// ---------------------------------------------------------------------------
// passC (R10 + window perm): per-bucket node sort in place (node-ordered CSR,
// locality identical to R10) PLUS a deg-rank permutation WITHIN each 16-node
// window -> each wave's 4 groups get adjacent-rank degrees (kills the
// max-over-4 chunk divergence) without touching which lines a block reads.
// ---------------------------------------------------------------------------
__global__ __launch_bounds__(512) void passC_sort(
    const int* __restrict__ gcur,
    int* __restrict__ binned,
    int* __restrict__ startg, int* __restrict__ degg,
    int* __restrict__ perm)
{
    __shared__ int lbuf[CAP];
    __shared__ int ldeg[512], sc2[512], lcur[512];
    int t = threadIdx.x, k = blockIdx.x;
    int ebase = k * CAP;
    int cnt = gcur[k * 16];
    if (cnt > CAP) cnt = CAP;

    ldeg[t] = 0;
    __syncthreads();
    for (int i = t; i < cnt; i += 512) {
        int pk = binned[ebase + i];
        lbuf[i] = pk;
        atomicAdd(&ldeg[pk >> 18], 1);
    }
    __syncthreads();
    int dgv = ldeg[t];
    sc2[t] = dgv;
    __syncthreads();
    for (int o = 1; o < 512; o <<= 1) {
        int u = (t >= o) ? sc2[t - o] : 0;
        __syncthreads();
        sc2[t] += u;
        __syncthreads();
    }
    int excl = sc2[t] - dgv;
    int n = k * 512 + t;
    startg[n] = ebase + excl;
    degg[n] = dgv;
    lcur[t] = excl;

    // deg-rank within the 16-node window (ties broken by index): locality-
    // preserving processing permutation for the gather.
    int wbase = t & ~15;
    int rank = 0;
    #pragma unroll
    for (int j = 0; j < 16; ++j) {
        int dj = ldeg[wbase + j];
        rank += (dj < dgv) || (dj == dgv && (wbase + j) < t);
    }
    perm[(k << 9) + wbase + rank] = n;
    __syncthreads();
    for (int i = t; i < cnt; i += 512) {
        int pk = lbuf[i];
        int sl = atomicAdd(&lcur[pk >> 18], 1);
        binned[ebase + sl] = pk & 0x3FFFF;
    }
}

// ---------------------------------------------------------------------------
// Gather + edge MLP (R7/R10-verified inner loop). Node ids come from the
// window-local deg-rank perm; CSR is node-ordered so the block's srcs lines
// are identical to R10. W2 applied once per node via LDS transpose. Fused
// pooling over the <=2 graphs a 16-node block spans.
// ---------------------------------------------------------------------------
__global__ __launch_bounds__(256) void node_gather_fused(
    const uint4* __restrict__ px16,
    const int* __restrict__ srcs, const int* __restrict__ startg,
    const int* __restrict__ degg, const int* __restrict__ perm,
    const float* __restrict__ W1, const float* __restrict__ b1,
    const float* __restrict__ W2, const float* __restrict__ b2,
    const float* __restrict__ Wp, const float* __restrict__ bp,
    const int* __restrict__ batch,
    float* __restrict__ out_s, float* __restrict__ pooled)
{
    __shared__ uint4 sepk[16][17];   // staged edges: {x01,x23,dist,pad}
    __shared__ float smh[16][20];    // sumH transpose (padded rows)

    int t = threadIdx.x;
    int g = t & 15;
    int grp = t >> 4;
    int n = perm[blockIdx.x * 16 + grp];

    // per-lane weights (registers)
    float w1c0 = W1[0 * 16 + g], w1c1 = W1[1 * 16 + g];
    float w1c2 = W1[2 * 16 + g], w1c3 = W1[3 * 16 + g];
    half2v wh45, wh67;
    wh45[0] = (_Float16)W1[4 * 16 + g];
    wh45[1] = (_Float16)W1[5 * 16 + g];
    wh67[0] = (_Float16)W1[6 * 16 + g];
    wh67[1] = (_Float16)W1[7 * 16 + g];
    float w1c8 = W1[8 * 16 + g];
    float b1g = b1[g], b2g = b2[g];
    float w2col[16];
    #pragma unroll
    for (int i = 0; i < 16; ++i) w2col[i] = W2[i * 16 + g];  // column g
    float wp0 = Wp[2 * g], wp1 = Wp[2 * g + 1];

    int base = startg[n];
    int dg = degg[n];

    // self record
    uint4 rn = px16[n];
    float2 f01 = __half22float2(*(__half2*)&rn.x);
    float2 f23 = __half22float2(*(__half2*)&rn.y);
    float2 f45 = __half22float2(*(__half2*)&rn.z);
    float2 f67 = __half22float2(*(__half2*)&rn.w);
    float pnx = f45.x, pny = f45.y, pnz = f67.x;
    float pre = b1g + f01.x * w1c0 + f01.y * w1c1 + f23.x * w1c2 + f23.y * w1c3;

    float sumH = 0.0f;

    // pipeline prologue
    int sC = 0;
    if (g < dg) sC = srcs[base + g];
    uint4 rC = px16[sC];
    int sN = sC;
    if (16 + g < dg) sN = srcs[base + 16 + g];

    for (int k0 = 0; k0 < dg; k0 += 16) {
        int rem = dg - k0;
        int cnt = rem < 16 ? rem : 16;
        if (g < cnt) {
            float2 e45 = __half22float2(*(__half2*)&rC.z);
            float2 e67 = __half22float2(*(__half2*)&rC.w);
            float dx = e45.x - pnx, dy = e45.y - pny, dz = e67.x - pnz;
            float dist = sqrtf(dx * dx + dy * dy + dz * dz);
            sepk[grp][g] = make_uint4(rC.x, rC.y, __float_as_uint(dist), 0u);
        }
        // issue next chunk's loads
        uint4 rNext = px16[sN];
        int sNN = sN;
        if (k0 + 32 + g < dg) sNN = srcs[base + k0 + 32 + g];
        // compute current chunk from LDS (2x unrolled to batch waits)
        int j = 0;
        for (; j + 1 < cnt; j += 2) {
            uint4 A = sepk[grp][j];
            uint4 B = sepk[grp][j + 1];
            float a = fmaf(__uint_as_float(A.z), w1c8, pre);
            a = __builtin_amdgcn_fdot2(u2h(A.x), wh45, a, false);
            a = __builtin_amdgcn_fdot2(u2h(A.y), wh67, a, false);
            sumH += a * __builtin_amdgcn_rcpf(1.0f + __expf(-a));
            float b = fmaf(__uint_as_float(B.z), w1c8, pre);
            b = __builtin_amdgcn_fdot2(u2h(B.x), wh45, b, false);
            b = __builtin_amdgcn_fdot2(u2h(B.y), wh67, b, false);
            sumH += b * __builtin_amdgcn_rcpf(1.0f + __expf(-b));
        }
        if (j < cnt) {
            uint4 A = sepk[grp][j];
            float a = fmaf(__uint_as_float(A.z), w1c8, pre);
            a = __builtin_amdgcn_fdot2(u2h(A.x), wh45, a, false);
            a = __builtin_amdgcn_fdot2(u2h(A.y), wh67, a, false);
            sumH += a * __builtin_amdgcn_rcpf(1.0f + __expf(-a));
        }
        rC = rNext;
        sN = sNN;
    }

    // LDS-transpose epilogue: lane g applies W2 column g.
    smh[grp][g] = sumH;
    float4 s0v = *(const float4*)&smh[grp][0];
    float4 s1v = *(const float4*)&smh[grp][4];
    float4 s2v = *(const float4*)&smh[grp][8];
    float4 s3v = *(const float4*)&smh[grp][12];
    float red = s0v.x * w2col[0] + s0v.y * w2col[1] + s0v.z * w2col[2] + s0v.w * w2col[3]
              + s1v.x * w2col[4] + s1v.y * w2col[5] + s1v.z * w2col[6] + s1v.w * w2col[7]
              + s2v.x * w2col[8] + s2v.y * w2col[9] + s2v.z * w2col[10] + s2v.w * w2col[11]
              + s3v.x * w2col[12] + s3v.y * w2col[13] + s3v.z * w2col[14] + s3v.w * w2col[15];

    float fdg = (float)dg;
    float inv = 1.0f / fmaxf(fdg, 1.0f);
    float h = fmaxf((red + fdg * b2g) * inv, 0.0f);

    // logits via 16-lane allreduce
    float c0 = h * wp0, c1 = h * wp1;
    #pragma unroll
    for (int mset = 8; mset > 0; mset >>= 1) {
        c0 += __shfl_xor(c0, mset);
        c1 += __shfl_xor(c1, mset);
    }
    float l0 = c0 + bp[0], l1 = c1 + bp[1];
    float mx = fmaxf(l0, l1);
    float e0s = __expf(l0 - mx), e1s = __expf(l1 - mx);
    float isum = 1.0f / (e0s + e1s);
    float s0 = e0s * isum, s1 = e1s * isum;

    if (g == 0) ((float2*)out_s)[n] = make_float2(s0, s1);

    // fused pooling: block's node set is still [16b,16b+16) -> <=2 graphs
    __shared__ float lpool[2][32];
    __shared__ int sg0;
    if (t == 0) sg0 = batch[blockIdx.x * 16];
    if (t < 64) lpool[t >> 5][t & 31] = 0.0f;
    __syncthreads();

    int gid = batch[n];
    int idx = gid - sg0;
    float p0 = s0 * h, p1 = s1 * h;
    if (idx < 2) {
        atomicAdd(&lpool[idx][g], p0);
        atomicAdd(&lpool[idx][16 + g], p1);
    } else {  // pathological tiny-graph fallback
        atomicAdd(&pooled[gid * 32 + g], p0);
        atomicAdd(&pooled[gid * 32 + 16 + g], p1);
    }
    __syncthreads();
    if (t < 32) {
        float v = lpool[0][t];
        if (v != 0.0f) atomicAdd(&pooled[sg0 * 32 + t], v);
        v = lpool[1][t];
        if (v != 0.0f) atomicAdd(&pooled[(sg0 + 1) * 32 + t], v);
    }
}

// ---------------------------------------------------------------------------
// z = pooled.reshape(G,32) @ Wz + bz
// ---------------------------------------------------------------------------
__global__ __launch_bounds__(256) void z_kernel(const float* __restrict__ pooled,
                                                const float* __restrict__ Wz,
                                                const float* __restrict__ bz,
                                                float* __restrict__ out_z) {
    int idx = blockIdx.x * 256 + threadIdx.x;
    if (idx >= N_GRAPHS * 8) return;
    int gph = idx >> 3, o = idx & 7;
    float a = bz[o];
    const float* pp = pooled + (size_t)gph * 32;
    #pragma unroll
    for (int j = 0; j < 32; ++j) a = fmaf(pp[j], Wz[j * 8 + o], a);
    out_z[idx] = a;
}

extern "C" void kernel_launch(void* const* d_in, const int* in_sizes, int n_in,
                              void* d_out, int out_size, void* d_ws, size_t ws_size,
                              hipStream_t stream) {
    const float* x    = (const float*)d_in[0];
    const float* pos  = (const float*)d_in[1];
    const float* W1   = (const float*)d_in[2];
    const float* b1   = (const float*)d_in[3];
    const float* W2   = (const float*)d_in[4];
    const float* b2   = (const float*)d_in[5];
    const float* Wp   = (const float*)d_in[6];
    const float* bp   = (const float*)d_in[7];
    const float* Wz   = (const float*)d_in[8];
    const float* bz   = (const float*)d_in[9];
    const int*   ei   = (const int*)d_in[10];
    const int*   batch= (const int*)d_in[11];
    float* out = (float*)d_out;
    float* out_z = out;                   // [1024*8]
    float* out_s = out + N_GRAPHS * 8;    // [262144*2]

    // ws (ints): gcur[NBK*16] | binned[NBK*CAP] (=srcs after passC) |
    //            startg[N] | degg[N] | perm[N] | pooled[1025*32] | px16[N uint4]
    int* gcur     = (int*)d_ws;
    int* binned   = gcur + NBK * 16;
    int* startg   = binned + (size_t)NBK * CAP;
    int* degg     = startg + N_NODES;
    int* perm     = degg + N_NODES;
    float* pooled = (float*)(perm + N_NODES);
    uint4* px16   = (uint4*)(pooled + 1025 * 32);   // offset is 16B-aligned

    hipMemsetAsync(gcur, 0, NBK * 16 * sizeof(int), stream);
    fusedAB<<<ABLK, 256, 0, stream>>>(ei, x, pos, gcur, binned, px16, pooled);
    passC_sort<<<NBK, 512, 0, stream>>>(gcur, binned, startg, degg, perm);
    node_gather_fused<<<N_NODES / 16, 256, 0, stream>>>(
        px16, binned, startg, degg, perm, W1, b1, W2, b2, Wp, bp, batch, out_s, pooled);
    z_kernel<<<32, 256, 0, stream>>>(pooled, Wz, bz, out_z);
}

// Round 17
// 173.897 us; speedup vs baseline: 2.3347x; 1.0113x over previous
//
#include <hip/hip_runtime.h>
#include <hip/hip_fp16.h>
#include <math.h>

#define N_NODES 262144
#define N_EDGES 4194304
#define N_GRAPHS 1024
#define NBK 512                  // dst buckets (512 nodes each)
#define CAP 8960                 // per-bucket capacity (mean 8192 + 8.5 sigma)
#define ABLK 512                 // fusedAB blocks
#define AEPB (N_EDGES / ABLK)    // 8192 edges per block; run = 16 edges = 64B

typedef _Float16 half2v __attribute__((ext_vector_type(2)));
__device__ inline half2v u2h(unsigned u) { union { unsigned u; half2v h; } c; c.u = u; return c.h; }
__device__ inline unsigned packh2(float a, float b) {
    union { __half2 h; unsigned u; } c; c.h = __floats2half2_rn(a, b); return c.u;
}

// ---------------------------------------------------------------------------
// fusedAB: pack px16 + zero pooled + dual-sub-histogram (halves LDS-atomic
// conflicts) + global range reservation + line-dense binned scatter with
// int4-vectorized ei reads. Plain (cached) loads/stores throughout —
// nt measured net-negative (R14/R15).
// ---------------------------------------------------------------------------
__global__ __launch_bounds__(256) void fusedAB(
    const int* __restrict__ ei, const float* __restrict__ x,
    const float* __restrict__ pos, int* __restrict__ gcur,
    int* __restrict__ binned, uint4* __restrict__ px16,
    float* __restrict__ pooled)
{
    __shared__ int lh2[2][NBK];
    int t = threadIdx.x, b = blockIdx.x;
    int half = (t >> 6) & 1;     // wave parity -> private sub-histogram

    // pack 2 nodes per thread (fp16 x4 + pos3 -> one 16B record, 4MB total)
    #pragma unroll
    for (int k = 0; k < 2; ++k) {
        int n = b * 512 + k * 256 + t;
        float4 v = ((const float4*)x)[n];
        float p0 = pos[3 * n], p1 = pos[3 * n + 1], p2 = pos[3 * n + 2];
        uint4 r;
        r.x = packh2(v.x, v.y);
        r.y = packh2(v.z, v.w);
        r.z = packh2(p0, p1);
        r.w = packh2(p2, 0.0f);
        px16[n] = r;
    }
    int pid = b * 256 + t;
    if (pid < 1025 * 32) pooled[pid] = 0.0f;

    #pragma unroll
    for (int k = 0; k < 2; ++k) {
        lh2[0][t + 256 * k] = 0;
        lh2[1][t + 256 * k] = 0;
    }
    __syncthreads();

    const int4* dsts = (const int4*)(ei + N_EDGES + b * AEPB);
    #pragma unroll
    for (int i = 0; i < AEPB / 1024; ++i) {
        int4 d4 = dsts[i * 256 + t];
        atomicAdd(&lh2[half][d4.x >> 9], 1);
        atomicAdd(&lh2[half][d4.y >> 9], 1);
        atomicAdd(&lh2[half][d4.z >> 9], 1);
        atomicAdd(&lh2[half][d4.w >> 9], 1);
    }
    __syncthreads();
    #pragma unroll
    for (int k = 0; k < 2; ++k) {
        int kb = t + 256 * k;
        int tot = lh2[0][kb] + lh2[1][kb];
        lh2[0][kb] = atomicAdd(&gcur[kb * 16], tot);   // reserved base cursor
    }
    __syncthreads();
    const int4* srcp = (const int4*)(ei + b * AEPB);
    #pragma unroll
    for (int i = 0; i < AEPB / 1024; ++i) {
        int4 s4 = srcp[i * 256 + t];
        int4 d4 = dsts[i * 256 + t];
        int slot;
        slot = atomicAdd(&lh2[0][d4.x >> 9], 1);
        if (slot < CAP) binned[(size_t)(d4.x >> 9) * CAP + slot] = s4.x | ((d4.x & 511) << 18);
        slot = atomicAdd(&lh2[0][d4.y >> 9], 1);
        if (slot < CAP) binned[(size_t)(d4.y >> 9) * CAP + slot] = s4.y | ((d4.y & 511) << 18);
        slot = atomicAdd(&lh2[0][d4.z >> 9], 1);
        if (slot < CAP) binned[(size_t)(d4.z >> 9) * CAP + slot] = s4.z | ((d4.z & 511) << 18);
        slot = atomicAdd(&lh2[0][d4.w >> 9], 1);
        if (slot < CAP) binned[(size_t)(d4.w >> 9) * CAP + slot] = s4.w | ((d4.w & 511) << 18);
    }
}

// ---------------------------------------------------------------------------
// passC: per-bucket node sort in place (node-ordered CSR, R16 locality) +
// window-local deg-rank perm, emitted as packed ndesc {start, deg, node, 0}.
// Scan via wave shfl: 2 barriers in the scan path instead of 18.
// ---------------------------------------------------------------------------
__global__ __launch_bounds__(512) void passC_sort(
    const int* __restrict__ gcur,
    int* __restrict__ binned,
    int4* __restrict__ ndesc)
{
    __shared__ int lbuf[CAP];
    __shared__ int ldeg[512], lcur[512];
    __shared__ int wsum[8];
    int t = threadIdx.x, k = blockIdx.x;
    int ebase = k * CAP;
    int cnt = gcur[k * 16];
    if (cnt > CAP) cnt = CAP;

    ldeg[t] = 0;
    __syncthreads();
    for (int i = t; i < cnt; i += 512) {
        int pk = binned[ebase + i];
        lbuf[i] = pk;
        atomicAdd(&ldeg[pk >> 18], 1);
    }
    __syncthreads();
    int dgv = ldeg[t];

    // inclusive scan across 512 threads: wave-level shfl + cross-wave fixup
    int lane = t & 63, wid = t >> 6;
    int sv = dgv;
    #pragma unroll
    for (int o = 1; o < 64; o <<= 1) {
        int u = __shfl_up(sv, o);
        if (lane >= o) sv += u;
    }
    if (lane == 63) wsum[wid] = sv;
    __syncthreads();
    int pref = 0;
    #pragma unroll
    for (int w = 0; w < 8; ++w) pref += (w < wid) ? wsum[w] : 0;
    int excl = sv + pref - dgv;

    int n = k * 512 + t;
    lcur[t] = excl;

    // deg-rank within the 16-node window (ties by index): locality-preserving
    int wbase = t & ~15;
    int rank = 0;
    #pragma unroll
    for (int j = 0; j < 16; ++j) {
        int dj = ldeg[wbase + j];
        rank += (dj < dgv) || (dj == dgv && (wbase + j) < t);
    }
    ndesc[(k << 9) + wbase + rank] = make_int4(ebase + excl, dgv, n, 0);
    __syncthreads();
    for (int i = t; i < cnt; i += 512) {
        int pk = lbuf[i];
        int sl = atomicAdd(&lcur[pk >> 18], 1);
        binned[ebase + sl] = pk & 0x3FFFF;
    }
}

// ---------------------------------------------------------------------------
// Gather + edge MLP (R7/R16-verified inner loop). Node meta from one packed
// ndesc int4; px16 record prefetch now 2 chunks deep (double the latency
// coverage for L2/HBM misses). Fused pooling over <=2 graphs per block.
// ---------------------------------------------------------------------------
__global__ __launch_bounds__(256) void node_gather_fused(
    const uint4* __restrict__ px16,
    const int* __restrict__ srcs, const int4* __restrict__ ndesc,
    const float* __restrict__ W1, const float* __restrict__ b1,
    const float* __restrict__ W2, const float* __restrict__ b2,
    const float* __restrict__ Wp, const float* __restrict__ bp,
    const int* __restrict__ batch,
    float* __restrict__ out_s, float* __restrict__ pooled)
{
    __shared__ uint4 sepk[16][17];   // staged edges: {x01,x23,dist,pad}
    __shared__ float smh[16][20];    // sumH transpose (padded rows)

    int t = threadIdx.x;
    int g = t & 15;
    int grp = t >> 4;
    int4 nd = ndesc[blockIdx.x * 16 + grp];
    int base = nd.x, dg = nd.y, n = nd.z;

    // per-lane weights (registers)
    float w1c0 = W1[0 * 16 + g], w1c1 = W1[1 * 16 + g];
    float w1c2 = W1[2 * 16 + g], w1c3 = W1[3 * 16 + g];
    half2v wh45, wh67;
    wh45[0] = (_Float16)W1[4 * 16 + g];
    wh45[1] = (_Float16)W1[5 * 16 + g];
    wh67[0] = (_Float16)W1[6 * 16 + g];
    wh67[1] = (_Float16)W1[7 * 16 + g];
    float w1c8 = W1[8 * 16 + g];
    float b1g = b1[g], b2g = b2[g];
    float w2col[16];
    #pragma unroll
    for (int i = 0; i < 16; ++i) w2col[i] = W2[i * 16 + g];  // column g
    float wp0 = Wp[2 * g], wp1 = Wp[2 * g + 1];

    // self record
    uint4 rn = px16[n];
    float2 f01 = __half22float2(*(__half2*)&rn.x);
    float2 f23 = __half22float2(*(__half2*)&rn.y);
    float2 f45 = __half22float2(*(__half2*)&rn.z);
    float2 f67 = __half22float2(*(__half2*)&rn.w);
    float pnx = f45.x, pny = f45.y, pnz = f67.x;
    float pre = b1g + f01.x * w1c0 + f01.y * w1c1 + f23.x * w1c2 + f23.y * w1c3;

    float sumH = 0.0f;

    // pipeline prologue: 2 chunks of records in flight
    int sC = 0, sN, sNN;
    if (g < dg) sC = srcs[base + g];
    sN = sC;
    if (16 + g < dg) sN = srcs[base + 16 + g];
    sNN = sN;
    if (32 + g < dg) sNN = srcs[base + 32 + g];
    uint4 rC = px16[sC];
    uint4 rN = px16[sN];

    for (int k0 = 0; k0 < dg; k0 += 16) {
        int rem = dg - k0;
        int cnt = rem < 16 ? rem : 16;
        if (g < cnt) {
            float2 e45 = __half22float2(*(__half2*)&rC.z);
            float2 e67 = __half22float2(*(__half2*)&rC.w);
            float dx = e45.x - pnx, dy = e45.y - pny, dz = e67.x - pnz;
            float dist = sqrtf(dx * dx + dy * dy + dz * dz);
            sepk[grp][g] = make_uint4(rC.x, rC.y, __float_as_uint(dist), 0u);
        }
        // issue chunk k+2's record load and chunk k+3's src ids
        uint4 rNN = px16[sNN];
        int sNNN = sNN;
        if (k0 + 48 + g < dg) sNNN = srcs[base + k0 + 48 + g];
        // compute current chunk from LDS (2x unrolled to batch waits)
        int j = 0;
        for (; j + 1 < cnt; j += 2) {
            uint4 A = sepk[grp][j];
            uint4 B = sepk[grp][j + 1];
            float a = fmaf(__uint_as_float(A.z), w1c8, pre);
            a = __builtin_amdgcn_fdot2(u2h(A.x), wh45, a, false);
            a = __builtin_amdgcn_fdot2(u2h(A.y), wh67, a, false);
            sumH += a * __builtin_amdgcn_rcpf(1.0f + __expf(-a));
            float b = fmaf(__uint_as_float(B.z), w1c8, pre);
            b = __builtin_amdgcn_fdot2(u2h(B.x), wh45, b, false);
            b = __builtin_amdgcn_fdot2(u2h(B.y), wh67, b, false);
            sumH += b * __builtin_amdgcn_rcpf(1.0f + __expf(-b));
        }
        if (j < cnt) {
            uint4 A = sepk[grp][j];
            float a = fmaf(__uint_as_float(A.z), w1c8, pre);
            a = __builtin_amdgcn_fdot2(u2h(A.x), wh45, a, false);
            a = __builtin_amdgcn_fdot2(u2h(A.y), wh67, a, false);
            sumH += a * __builtin_amdgcn_rcpf(1.0f + __expf(-a));
        }
        rC = rN; rN = rNN; sNN = sNNN;
    }

    // LDS-transpose epilogue: lane g applies W2 column g.
    smh[grp][g] = sumH;
    float4 s0v = *(const float4*)&smh[grp][0];
    float4 s1v = *(const float4*)&smh[grp][4];
    float4 s2v = *(const float4*)&smh[grp][8];
    float4 s3v = *(const float4*)&smh[grp][12];
    float red = s0v.x * w2col[0] + s0v.y * w2col[1] + s0v.z * w2col[2] + s0v.w * w2col[3]
              + s1v.x * w2col[4] + s1v.y * w2col[5] + s1v.z * w2col[6] + s1v.w * w2col[7]
              + s2v.x * w2col[8] + s2v.y * w2col[9] + s2v.z * w2col[10] + s2v.w * w2col[11]
              + s3v.x * w2col[12] + s3v.y * w2col[13] + s3v.z * w2col[14] + s3v.w * w2col[15];

    float fdg = (float)dg;
    float inv = 1.0f / fmaxf(fdg, 1.0f);
    float h = fmaxf((red + fdg * b2g) * inv, 0.0f);

    // logits via 16-lane allreduce
    float c0 = h * wp0, c1 = h * wp1;
    #pragma unroll
    for (int mset = 8; mset > 0; mset >>= 1) {
        c0 += __shfl_xor(c0, mset);
        c1 += __shfl_xor(c1, mset);
    }
    float l0 = c0 + bp[0], l1 = c1 + bp[1];
    float mx = fmaxf(l0, l1);
    float e0s = __expf(l0 - mx), e1s = __expf(l1 - mx);
    float isum = 1.0f / (e0s + e1s);
    float s0 = e0s * isum, s1 = e1s * isum;

    if (g == 0) ((float2*)out_s)[n] = make_float2(s0, s1);

    // fused pooling: block's node set is still [16b,16b+16) -> <=2 graphs
    __shared__ float lpool[2][32];
    __shared__ int sg0;
    if (t == 0) sg0 = batch[blockIdx.x * 16];
    if (t < 64) lpool[t >> 5][t & 31] = 0.0f;
    __syncthreads();

    int gid = batch[n];
    int idx = gid - sg0;
    float p0 = s0 * h, p1 = s1 * h;
    if (idx < 2) {
        atomicAdd(&lpool[idx][g], p0);
        atomicAdd(&lpool[idx][16 + g], p1);
    } else {  // pathological tiny-graph fallback
        atomicAdd(&pooled[gid * 32 + g], p0);
        atomicAdd(&pooled[gid * 32 + 16 + g], p1);
    }
    __syncthreads();
    if (t < 32) {
        float v = lpool[0][t];
        if (v != 0.0f) atomicAdd(&pooled[sg0 * 32 + t], v);
        v = lpool[1][t];
        if (v != 0.0f) atomicAdd(&pooled[(sg0 + 1) * 32 + t], v);
    }
}

// ---------------------------------------------------------------------------
// z = pooled.reshape(G,32) @ Wz + bz
// ---------------------------------------------------------------------------
__global__ __launch_bounds__(256) void z_kernel(const float* __restrict__ pooled,
                                                const float* __restrict__ Wz,
                                                const float* __restrict__ bz,
                                                float* __restrict__ out_z) {
    int idx = blockIdx.x * 256 + threadIdx.x;
    if (idx >= N_GRAPHS * 8) return;
    int gph = idx >> 3, o = idx & 7;
    float a = bz[o];
    const float* pp = pooled + (size_t)gph * 32;
    #pragma unroll
    for (int j = 0; j < 32; ++j) a = fmaf(pp[j], Wz[j * 8 + o], a);
    out_z[idx] = a;
}

extern "C" void kernel_launch(void* const* d_in, const int* in_sizes, int n_in,
                              void* d_out, int out_size, void* d_ws, size_t ws_size,
                              hipStream_t stream) {
    const float* x    = (const float*)d_in[0];
    const float* pos  = (const float*)d_in[1];
    const float* W1   = (const float*)d_in[2];
    const float* b1   = (const float*)d_in[3];
    const float* W2   = (const float*)d_in[4];
    const float* b2   = (const float*)d_in[5];
    const float* Wp   = (const float*)d_in[6];
    const float* bp   = (const float*)d_in[7];
    const float* Wz   = (const float*)d_in[8];
    const float* bz   = (const float*)d_in[9];
    const int*   ei   = (const int*)d_in[10];
    const int*   batch= (const int*)d_in[11];
    float* out = (float*)d_out;
    float* out_z = out;                   // [1024*8]
    float* out_s = out + N_GRAPHS * 8;    // [262144*2]

    // ws (ints): gcur[NBK*16] | binned[NBK*CAP] (=srcs after passC) |
    //            ndesc[N int4] | pooled[1025*32] | px16[N uint4]
    int* gcur     = (int*)d_ws;
    int* binned   = gcur + NBK * 16;
    int4* ndesc   = (int4*)(binned + (size_t)NBK * CAP);   // 16B-aligned
    float* pooled = (float*)(ndesc + N_NODES);
    uint4* px16   = (uint4*)(pooled + 1025 * 32);          // 16B-aligned

    hipMemsetAsync(gcur, 0, NBK * 16 * sizeof(int), stream);
    fusedAB<<<ABLK, 256, 0, stream>>>(ei, x, pos, gcur, binned, px16, pooled);
    passC_sort<<<NBK, 512, 0, stream>>>(gcur, binned, ndesc);
    node_gather_fused<<<N_NODES / 16, 256, 0, stream>>>(
        px16, binned, ndesc, W1, b1, W2, b2, Wp, bp, batch, out_s, pooled);
    z_kernel<<<32, 256, 0, stream>>>(pooled, Wz, bz, out_z);
}

// Round 18
// 159.120 us; speedup vs baseline: 2.5515x; 1.0929x over previous
//
#include <hip/hip_runtime.h>
#include <hip/hip_fp16.h>
#include <math.h>

#define N_NODES 262144
#define N_EDGES 4194304
#define N_GRAPHS 1024
#define NBK 512                  // dst buckets (512 nodes each)
#define CAP 8960                 // per-bucket capacity (mean 8192 + 8.5 sigma)
#define ABLK 512                 // fusedAB blocks
#define AEPB (N_EDGES / ABLK)    // 8192 edges per block; run = 16 edges = 64B

typedef _Float16 half2v __attribute__((ext_vector_type(2)));
__device__ inline half2v u2h(unsigned u) { union { unsigned u; half2v h; } c; c.u = u; return c.h; }
__device__ inline unsigned packh2(float a, float b) {
    union { __half2 h; unsigned u; } c; c.h = __floats2half2_rn(a, b); return c.u;
}

// ---------------------------------------------------------------------------
// fusedAB (R17-verified): pack px16 + zero pooled + dual-sub-histogram +
// global range reservation + line-dense binned scatter, int4 ei reads.
// ---------------------------------------------------------------------------
__global__ __launch_bounds__(256) void fusedAB(
    const int* __restrict__ ei, const float* __restrict__ x,
    const float* __restrict__ pos, int* __restrict__ gcur,
    int* __restrict__ binned, uint4* __restrict__ px16,
    float* __restrict__ pooled)
{
    __shared__ int lh2[2][NBK];
    int t = threadIdx.x, b = blockIdx.x;
    int half = (t >> 6) & 1;     // wave parity -> private sub-histogram

    #pragma unroll
    for (int k = 0; k < 2; ++k) {
        int n = b * 512 + k * 256 + t;
        float4 v = ((const float4*)x)[n];
        float p0 = pos[3 * n], p1 = pos[3 * n + 1], p2 = pos[3 * n + 2];
        uint4 r;
        r.x = packh2(v.x, v.y);
        r.y = packh2(v.z, v.w);
        r.z = packh2(p0, p1);
        r.w = packh2(p2, 0.0f);
        px16[n] = r;
    }
    int pid = b * 256 + t;
    if (pid < 1025 * 32) pooled[pid] = 0.0f;

    #pragma unroll
    for (int k = 0; k < 2; ++k) {
        lh2[0][t + 256 * k] = 0;
        lh2[1][t + 256 * k] = 0;
    }
    __syncthreads();

    const int4* dsts = (const int4*)(ei + N_EDGES + b * AEPB);
    #pragma unroll
    for (int i = 0; i < AEPB / 1024; ++i) {
        int4 d4 = dsts[i * 256 + t];
        atomicAdd(&lh2[half][d4.x >> 9], 1);
        atomicAdd(&lh2[half][d4.y >> 9], 1);
        atomicAdd(&lh2[half][d4.z >> 9], 1);
        atomicAdd(&lh2[half][d4.w >> 9], 1);
    }
    __syncthreads();
    #pragma unroll
    for (int k = 0; k < 2; ++k) {
        int kb = t + 256 * k;
        int tot = lh2[0][kb] + lh2[1][kb];
        lh2[0][kb] = atomicAdd(&gcur[kb * 16], tot);   // reserved base cursor
    }
    __syncthreads();
    const int4* srcp = (const int4*)(ei + b * AEPB);
    #pragma unroll
    for (int i = 0; i < AEPB / 1024; ++i) {
        int4 s4 = srcp[i * 256 + t];
        int4 d4 = dsts[i * 256 + t];
        int slot;
        slot = atomicAdd(&lh2[0][d4.x >> 9], 1);
        if (slot < CAP) binned[(size_t)(d4.x >> 9) * CAP + slot] = s4.x | ((d4.x & 511) << 18);
        slot = atomicAdd(&lh2[0][d4.y >> 9], 1);
        if (slot < CAP) binned[(size_t)(d4.y >> 9) * CAP + slot] = s4.y | ((d4.y & 511) << 18);
        slot = atomicAdd(&lh2[0][d4.z >> 9], 1);
        if (slot < CAP) binned[(size_t)(d4.z >> 9) * CAP + slot] = s4.z | ((d4.z & 511) << 18);
        slot = atomicAdd(&lh2[0][d4.w >> 9], 1);
        if (slot < CAP) binned[(size_t)(d4.w >> 9) * CAP + slot] = s4.w | ((d4.w & 511) << 18);
    }
}

// ---------------------------------------------------------------------------
// bucket_fused: one 512-thread block per 512-node bucket. Loads bucket edges
// to LDS ONCE, sorts node-grouped in place (register-staged permute), then
// runs the R17-verified MLP gather with srcs from LDS (no CSR write/read,
// no srcs global stream -> px16 stays L2-resident). Window-local deg-rank
// order preserves the R16 divergence fix. Fused pooling per bucket.
// ---------------------------------------------------------------------------
__global__ __launch_bounds__(512) void bucket_fused(
    const int* __restrict__ gcur, const int* __restrict__ binned,
    const uint4* __restrict__ px16,
    const float* __restrict__ W1, const float* __restrict__ b1,
    const float* __restrict__ W2, const float* __restrict__ b2,
    const float* __restrict__ Wp, const float* __restrict__ bp,
    const int* __restrict__ batch,
    float* __restrict__ out_s, float* __restrict__ pooled)
{
    __shared__ int lbuf[CAP];
    __shared__ int ldegs[512], lstart[512], lcur[512], lperm[512];
    __shared__ int bloc[512];
    __shared__ int wsum[8];
    __shared__ uint4 sepk[32][17];
    __shared__ float smh[32][20];
    __shared__ float lpool[8][33];

    int t = threadIdx.x, k = blockIdx.x;
    int ebase = k * CAP;
    int cnt = gcur[k * 16];
    if (cnt > CAP) cnt = CAP;

    ldegs[t] = 0;
    bloc[t] = batch[(k << 9) + t];
    for (int i = t; i < 8 * 33; i += 512) ((float*)lpool)[i] = 0.0f;
    __syncthreads();

    // 1) stage bucket edges in LDS + per-node degree histogram
    for (int i = t; i < cnt; i += 512) {
        int pk = binned[ebase + i];
        lbuf[i] = pk;
        atomicAdd(&ldegs[pk >> 18], 1);
    }
    __syncthreads();
    int dgv = ldegs[t];

    // 2) inclusive scan (wave shfl + cross-wave fixup)
    int lane = t & 63, wid = t >> 6;
    int sv = dgv;
    #pragma unroll
    for (int o = 1; o < 64; o <<= 1) {
        int u = __shfl_up(sv, o);
        if (lane >= o) sv += u;
    }
    if (lane == 63) wsum[wid] = sv;
    __syncthreads();
    int pref = 0;
    #pragma unroll
    for (int w = 0; w < 8; ++w) pref += (w < wid) ? wsum[w] : 0;
    int excl = sv + pref - dgv;
    lstart[t] = excl;
    lcur[t] = excl;

    // 3) deg-rank within each 16-node window (ties by index)
    int wbase = t & ~15;
    int rank = 0;
    #pragma unroll
    for (int j = 0; j < 16; ++j) {
        int dj = ldegs[wbase + j];
        rank += (dj < dgv) || (dj == dgv && (wbase + j) < t);
    }
    lperm[wbase + rank] = t;
    __syncthreads();

    // 4) in-place node-group permute: register-stage all edges (static idx)
    int regpk[18];
    #pragma unroll
    for (int c = 0; c < 18; ++c) {
        int i = t + c * 512;
        regpk[c] = (i < cnt) ? lbuf[i] : -1;
    }
    __syncthreads();
    #pragma unroll
    for (int c = 0; c < 18; ++c) {
        int pk = regpk[c];
        if (pk >= 0) {
            int sl = atomicAdd(&lcur[pk >> 18], 1);
            lbuf[sl] = pk & 0x3FFFF;   // src id, grouped by local node
        }
    }
    __syncthreads();

    // ---- MLP gather phase (R17-verified math) ----
    int g = t & 15, grp = t >> 4;    // 32 groups x 16 lanes

    float w1c0 = W1[0 * 16 + g], w1c1 = W1[1 * 16 + g];
    float w1c2 = W1[2 * 16 + g], w1c3 = W1[3 * 16 + g];
    half2v wh45, wh67;
    wh45[0] = (_Float16)W1[4 * 16 + g];
    wh45[1] = (_Float16)W1[5 * 16 + g];
    wh67[0] = (_Float16)W1[6 * 16 + g];
    wh67[1] = (_Float16)W1[7 * 16 + g];
    float w1c8 = W1[8 * 16 + g];
    float b1g = b1[g], b2g = b2[g];
    float w2col[16];
    #pragma unroll
    for (int i = 0; i < 16; ++i) w2col[i] = W2[i * 16 + g];
    float wp0 = Wp[2 * g], wp1 = Wp[2 * g + 1];
    int sg0 = bloc[0];

    for (int nn = 0; nn < 16; ++nn) {
        int w = lperm[grp * 16 + nn];      // local node id (window deg-rank)
        int n = (k << 9) + w;
        int base = lstart[w];
        int dg = ldegs[w];

        uint4 rn = px16[n];
        float2 f01 = __half22float2(*(__half2*)&rn.x);
        float2 f23 = __half22float2(*(__half2*)&rn.y);
        float2 f45 = __half22float2(*(__half2*)&rn.z);
        float2 f67 = __half22float2(*(__half2*)&rn.w);
        float pnx = f45.x, pny = f45.y, pnz = f67.x;
        float pre = b1g + f01.x * w1c0 + f01.y * w1c1 + f23.x * w1c2 + f23.y * w1c3;

        float sumH = 0.0f;

        int sC = (g < dg) ? lbuf[base + g] : 0;
        uint4 rC = px16[sC];
        int sN = (16 + g < dg) ? lbuf[base + 16 + g] : sC;

        for (int k0 = 0; k0 < dg; k0 += 16) {
            int rem = dg - k0;
            int cc = rem < 16 ? rem : 16;
            if (g < cc) {
                float2 e45 = __half22float2(*(__half2*)&rC.z);
                float2 e67 = __half22float2(*(__half2*)&rC.w);
                float dx = e45.x - pnx, dy = e45.y - pny, dz = e67.x - pnz;
                float dist = sqrtf(dx * dx + dy * dy + dz * dz);
                sepk[grp][g] = make_uint4(rC.x, rC.y, __float_as_uint(dist), 0u);
            }
            uint4 rNext = px16[sN];
            int sNN = (k0 + 32 + g < dg) ? lbuf[base + k0 + 32 + g] : sN;
            int j = 0;
            for (; j + 1 < cc; j += 2) {
                uint4 A = sepk[grp][j];
                uint4 B = sepk[grp][j + 1];
                float a = fmaf(__uint_as_float(A.z), w1c8, pre);
                a = __builtin_amdgcn_fdot2(u2h(A.x), wh45, a, false);
                a = __builtin_amdgcn_fdot2(u2h(A.y), wh67, a, false);
                sumH += a * __builtin_amdgcn_rcpf(1.0f + __expf(-a));
                float bb = fmaf(__uint_as_float(B.z), w1c8, pre);
                bb = __builtin_amdgcn_fdot2(u2h(B.x), wh45, bb, false);
                bb = __builtin_amdgcn_fdot2(u2h(B.y), wh67, bb, false);
                sumH += bb * __builtin_amdgcn_rcpf(1.0f + __expf(-bb));
            }
            if (j < cc) {
                uint4 A = sepk[grp][j];
                float a = fmaf(__uint_as_float(A.z), w1c8, pre);
                a = __builtin_amdgcn_fdot2(u2h(A.x), wh45, a, false);
                a = __builtin_amdgcn_fdot2(u2h(A.y), wh67, a, false);
                sumH += a * __builtin_amdgcn_rcpf(1.0f + __expf(-a));
            }
            rC = rNext;
            sN = sNN;
        }

        // LDS-transpose epilogue: lane g applies W2 column g
        smh[grp][g] = sumH;
        float4 s0v = *(const float4*)&smh[grp][0];
        float4 s1v = *(const float4*)&smh[grp][4];
        float4 s2v = *(const float4*)&smh[grp][8];
        float4 s3v = *(const float4*)&smh[grp][12];
        float red = s0v.x * w2col[0] + s0v.y * w2col[1] + s0v.z * w2col[2] + s0v.w * w2col[3]
                  + s1v.x * w2col[4] + s1v.y * w2col[5] + s1v.z * w2col[6] + s1v.w * w2col[7]
                  + s2v.x * w2col[8] + s2v.y * w2col[9] + s2v.z * w2col[10] + s2v.w * w2col[11]
                  + s3v.x * w2col[12] + s3v.y * w2col[13] + s3v.z * w2col[14] + s3v.w * w2col[15];

        float fdg = (float)dg;
        float inv = 1.0f / fmaxf(fdg, 1.0f);
        float h = fmaxf((red + fdg * b2g) * inv, 0.0f);

        float c0 = h * wp0, c1 = h * wp1;
        #pragma unroll
        for (int mset = 8; mset > 0; mset >>= 1) {
            c0 += __shfl_xor(c0, mset);
            c1 += __shfl_xor(c1, mset);
        }
        float l0 = c0 + bp[0], l1 = c1 + bp[1];
        float mx = fmaxf(l0, l1);
        float e0s = __expf(l0 - mx), e1s = __expf(l1 - mx);
        float isum = 1.0f / (e0s + e1s);
        float s0 = e0s * isum, s1 = e1s * isum;

        if (g == 0) ((float2*)out_s)[n] = make_float2(s0, s1);

        int gid = bloc[w];
        int idx = gid - sg0;
        float p0 = s0 * h, p1 = s1 * h;
        if (idx < 8) {
            atomicAdd(&lpool[idx][g], p0);
            atomicAdd(&lpool[idx][16 + g], p1);
        } else {  // pathological many-tiny-graphs fallback
            atomicAdd(&pooled[gid * 32 + g], p0);
            atomicAdd(&pooled[gid * 32 + 16 + g], p1);
        }
    }
    __syncthreads();

    // flush bucket-local pooling rows (graph boundaries shared across buckets)
    if (t < 256) {
        int gi = t >> 5, c = t & 31;
        int ngr = bloc[511] - sg0 + 1;
        if (gi < ngr && gi < 8) {
            float v = lpool[gi][c];
            if (v != 0.0f) atomicAdd(&pooled[(sg0 + gi) * 32 + c], v);
        }
    }
}

// ---------------------------------------------------------------------------
// z = pooled.reshape(G,32) @ Wz + bz
// ---------------------------------------------------------------------------
__global__ __launch_bounds__(256) void z_kernel(const float* __restrict__ pooled,
                                                const float* __restrict__ Wz,
                                                const float* __restrict__ bz,
                                                float* __restrict__ out_z) {
    int idx = blockIdx.x * 256 + threadIdx.x;
    if (idx >= N_GRAPHS * 8) return;
    int gph = idx >> 3, o = idx & 7;
    float a = bz[o];
    const float* pp = pooled + (size_t)gph * 32;
    #pragma unroll
    for (int j = 0; j < 32; ++j) a = fmaf(pp[j], Wz[j * 8 + o], a);
    out_z[idx] = a;
}

extern "C" void kernel_launch(void* const* d_in, const int* in_sizes, int n_in,
                              void* d_out, int out_size, void* d_ws, size_t ws_size,
                              hipStream_t stream) {
    const float* x    = (const float*)d_in[0];
    const float* pos  = (const float*)d_in[1];
    const float* W1   = (const float*)d_in[2];
    const float* b1   = (const float*)d_in[3];
    const float* W2   = (const float*)d_in[4];
    const float* b2   = (const float*)d_in[5];
    const float* Wp   = (const float*)d_in[6];
    const float* bp   = (const float*)d_in[7];
    const float* Wz   = (const float*)d_in[8];
    const float* bz   = (const float*)d_in[9];
    const int*   ei   = (const int*)d_in[10];
    const int*   batch= (const int*)d_in[11];
    float* out = (float*)d_out;
    float* out_z = out;                   // [1024*8]
    float* out_s = out + N_GRAPHS * 8;    // [262144*2]

    // ws (ints): gcur[NBK*16] | binned[NBK*CAP] | pooled[1025*32] | px16[N uint4]
    int* gcur     = (int*)d_ws;
    int* binned   = gcur + NBK * 16;
    float* pooled = (float*)(binned + (size_t)NBK * CAP);
    uint4* px16   = (uint4*)(pooled + 1025 * 32);          // 16B-aligned

    hipMemsetAsync(gcur, 0, NBK * 16 * sizeof(int), stream);
    fusedAB<<<ABLK, 256, 0, stream>>>(ei, x, pos, gcur, binned, px16, pooled);
    bucket_fused<<<NBK, 512, 0, stream>>>(gcur, binned, px16, W1, b1, W2, b2,
                                          Wp, bp, batch, out_s, pooled);
    z_kernel<<<32, 256, 0, stream>>>(pooled, Wz, bz, out_z);
}

// Round 19
// 155.669 us; speedup vs baseline: 2.6081x; 1.0222x over previous
//
#include <hip/hip_runtime.h>
#include <hip/hip_fp16.h>
#include <math.h>

#define N_NODES 262144
#define N_EDGES 4194304
#define N_GRAPHS 1024
#define NBK 512                  // dst buckets (512 nodes each)
#define CAP 8960                 // per-bucket capacity (mean 8192 + 8.5 sigma)
#define SCAP 2560                // per-sub-bucket (128 nodes; mean 2048 + 11 sigma)
#define ABLK 512                 // fusedAB blocks
#define AEPB (N_EDGES / ABLK)    // 8192 edges per block; run = 16 edges = 64B

typedef _Float16 half2v __attribute__((ext_vector_type(2)));
__device__ inline half2v u2h(unsigned u) { union { unsigned u; half2v h; } c; c.u = u; return c.h; }
__device__ inline unsigned packh2(float a, float b) {
    union { __half2 h; unsigned u; } c; c.h = __floats2half2_rn(a, b); return c.u;
}

// ---------------------------------------------------------------------------
// fusedAB (R17-verified): pack px16 + zero pooled + dual-sub-histogram +
// global range reservation + line-dense binned scatter, int4 ei reads.
// ---------------------------------------------------------------------------
__global__ __launch_bounds__(256) void fusedAB(
    const int* __restrict__ ei, const float* __restrict__ x,
    const float* __restrict__ pos, int* __restrict__ gcur,
    int* __restrict__ binned, uint4* __restrict__ px16,
    float* __restrict__ pooled)
{
    __shared__ int lh2[2][NBK];
    int t = threadIdx.x, b = blockIdx.x;
    int half = (t >> 6) & 1;     // wave parity -> private sub-histogram

    #pragma unroll
    for (int k = 0; k < 2; ++k) {
        int n = b * 512 + k * 256 + t;
        float4 v = ((const float4*)x)[n];
        float p0 = pos[3 * n], p1 = pos[3 * n + 1], p2 = pos[3 * n + 2];
        uint4 r;
        r.x = packh2(v.x, v.y);
        r.y = packh2(v.z, v.w);
        r.z = packh2(p0, p1);
        r.w = packh2(p2, 0.0f);
        px16[n] = r;
    }
    int pid = b * 256 + t;
    if (pid < 1025 * 32) pooled[pid] = 0.0f;

    #pragma unroll
    for (int k = 0; k < 2; ++k) {
        lh2[0][t + 256 * k] = 0;
        lh2[1][t + 256 * k] = 0;
    }
    __syncthreads();

    const int4* dsts = (const int4*)(ei + N_EDGES + b * AEPB);
    #pragma unroll
    for (int i = 0; i < AEPB / 1024; ++i) {
        int4 d4 = dsts[i * 256 + t];
        atomicAdd(&lh2[half][d4.x >> 9], 1);
        atomicAdd(&lh2[half][d4.y >> 9], 1);
        atomicAdd(&lh2[half][d4.z >> 9], 1);
        atomicAdd(&lh2[half][d4.w >> 9], 1);
    }
    __syncthreads();
    #pragma unroll
    for (int k = 0; k < 2; ++k) {
        int kb = t + 256 * k;
        int tot = lh2[0][kb] + lh2[1][kb];
        lh2[0][kb] = atomicAdd(&gcur[kb * 16], tot);   // reserved base cursor
    }
    __syncthreads();
    const int4* srcp = (const int4*)(ei + b * AEPB);
    #pragma unroll
    for (int i = 0; i < AEPB / 1024; ++i) {
        int4 s4 = srcp[i * 256 + t];
        int4 d4 = dsts[i * 256 + t];
        int slot;
        slot = atomicAdd(&lh2[0][d4.x >> 9], 1);
        if (slot < CAP) binned[(size_t)(d4.x >> 9) * CAP + slot] = s4.x | ((d4.x & 511) << 18);
        slot = atomicAdd(&lh2[0][d4.y >> 9], 1);
        if (slot < CAP) binned[(size_t)(d4.y >> 9) * CAP + slot] = s4.y | ((d4.y & 511) << 18);
        slot = atomicAdd(&lh2[0][d4.z >> 9], 1);
        if (slot < CAP) binned[(size_t)(d4.z >> 9) * CAP + slot] = s4.z | ((d4.z & 511) << 18);
        slot = atomicAdd(&lh2[0][d4.w >> 9], 1);
        if (slot < CAP) binned[(size_t)(d4.w >> 9) * CAP + slot] = s4.w | ((d4.w & 511) << 18);
    }
}

// ---------------------------------------------------------------------------
// bucket_fused: 4 sub-blocks per bucket (grid NBK*4, 256 threads). Each reads
// the bucket's binned stream (co-bucket blocks share an XCD L2: bid layout
// sub*512+k, 512%8==0), keeps its 128 nodes' edges in LDS (~19KB total ->
// 8 blocks/CU, full wave occupancy), sorts node-grouped in place, then runs
// the verified MLP gather with srcs from LDS. Window deg-rank preserved.
// ---------------------------------------------------------------------------
__global__ __launch_bounds__(256) void bucket_fused(
    const int* __restrict__ gcur, const int* __restrict__ binned,
    const uint4* __restrict__ px16,
    const float* __restrict__ W1, const float* __restrict__ b1,
    const float* __restrict__ W2, const float* __restrict__ b2,
    const float* __restrict__ Wp, const float* __restrict__ bp,
    const int* __restrict__ batch,
    float* __restrict__ out_s, float* __restrict__ pooled)
{
    __shared__ int sbuf[SCAP];
    __shared__ int ldeg[128], lstart[128], lcur[128], lperm[128], bloc[128];
    __shared__ int wsum[2];
    __shared__ int scnt;
    __shared__ uint4 sepk[16][17];
    __shared__ float smh[16][20];
    __shared__ float lpool[4][33];

    int t = threadIdx.x;
    int k = blockIdx.x & (NBK - 1);      // bucket
    int sub = blockIdx.x >> 9;           // sub-bucket 0..3
    int ebase = k * CAP;
    int cnt = gcur[k * 16];
    if (cnt > CAP) cnt = CAP;

    if (t < 128) {
        ldeg[t] = 0;
        bloc[t] = batch[(k << 9) + (sub << 7) + t];
    }
    if (t < 4 * 33) ((float*)lpool)[t] = 0.0f;
    if (t == 0) scnt = 0;
    __syncthreads();

    // 1) single pass: filter my 128 nodes' edges into sbuf + degree histogram
    for (int i = t; i < cnt; i += 256) {
        int pk = binned[ebase + i];
        if (((pk >> 25) & 3) == sub) {
            atomicAdd(&ldeg[(pk >> 18) & 127], 1);
            int sl = atomicAdd(&scnt, 1);
            if (sl < SCAP) sbuf[sl] = pk;
        }
    }
    __syncthreads();
    int sc = scnt < SCAP ? scnt : SCAP;
    int dgv = (t < 128) ? ldeg[t] : 0;

    // 2) inclusive scan over 128 degrees (2 waves, shfl + fixup)
    int lane = t & 63, wid = t >> 6;
    int sv = dgv;
    #pragma unroll
    for (int o = 1; o < 64; o <<= 1) {
        int u = __shfl_up(sv, o);
        if (lane >= o) sv += u;
    }
    if (lane == 63 && wid < 2) wsum[wid] = sv;
    __syncthreads();
    int excl = sv + ((wid == 1) ? wsum[0] : 0) - dgv;
    if (t < 128) { lstart[t] = excl; lcur[t] = excl; }

    // 3) deg-rank within each 16-node window (ties by index)
    if (t < 128) {
        int wbase = t & ~15;
        int rank = 0;
        #pragma unroll
        for (int j = 0; j < 16; ++j) {
            int dj = ldeg[wbase + j];
            rank += (dj < dgv) || (dj == dgv && (wbase + j) < t);
        }
        lperm[wbase + rank] = t;
    }
    __syncthreads();

    // 4) in-place node-group permute via register staging (static indices)
    int regpk[10];
    #pragma unroll
    for (int c = 0; c < 10; ++c) {
        int i = t + c * 256;
        regpk[c] = (i < sc) ? sbuf[i] : -1;
    }
    __syncthreads();
    #pragma unroll
    for (int c = 0; c < 10; ++c) {
        int pk = regpk[c];
        if (pk >= 0) {
            int sl = atomicAdd(&lcur[(pk >> 18) & 127], 1);
            sbuf[sl] = pk & 0x3FFFF;   // src id, grouped by local node
        }
    }
    __syncthreads();

    // ---- MLP gather phase (R17-verified math); 16 groups x 8 node-rounds ----
    int g = t & 15, grp = t >> 4;

    float w1c0 = W1[0 * 16 + g], w1c1 = W1[1 * 16 + g];
    float w1c2 = W1[2 * 16 + g], w1c3 = W1[3 * 16 + g];
    half2v wh45, wh67;
    wh45[0] = (_Float16)W1[4 * 16 + g];
    wh45[1] = (_Float16)W1[5 * 16 + g];
    wh67[0] = (_Float16)W1[6 * 16 + g];
    wh67[1] = (_Float16)W1[7 * 16 + g];
    float w1c8 = W1[8 * 16 + g];
    float b1g = b1[g], b2g = b2[g];
    float w2col[16];
    #pragma unroll
    for (int i = 0; i < 16; ++i) w2col[i] = W2[i * 16 + g];
    float wp0 = Wp[2 * g], wp1 = Wp[2 * g + 1];
    int sg0 = bloc[0];

    for (int nn = 0; nn < 8; ++nn) {
        int w = lperm[nn * 16 + grp];    // local node (window deg-rank order)
        int n = (k << 9) + (sub << 7) + w;
        int base = lstart[w];
        int dg = ldeg[w];

        uint4 rn = px16[n];
        float2 f01 = __half22float2(*(__half2*)&rn.x);
        float2 f23 = __half22float2(*(__half2*)&rn.y);
        float2 f45 = __half22float2(*(__half2*)&rn.z);
        float2 f67 = __half22float2(*(__half2*)&rn.w);
        float pnx = f45.x, pny = f45.y, pnz = f67.x;
        float pre = b1g + f01.x * w1c0 + f01.y * w1c1 + f23.x * w1c2 + f23.y * w1c3;

        float sumH = 0.0f;

        int sC = (g < dg) ? sbuf[base + g] : 0;
        uint4 rC = px16[sC];
        int sN = (16 + g < dg) ? sbuf[base + 16 + g] : sC;

        for (int k0 = 0; k0 < dg; k0 += 16) {
            int rem = dg - k0;
            int cc = rem < 16 ? rem : 16;
            if (g < cc) {
                float2 e45 = __half22float2(*(__half2*)&rC.z);
                float2 e67 = __half22float2(*(__half2*)&rC.w);
                float dx = e45.x - pnx, dy = e45.y - pny, dz = e67.x - pnz;
                float dist = sqrtf(dx * dx + dy * dy + dz * dz);
                sepk[grp][g] = make_uint4(rC.x, rC.y, __float_as_uint(dist), 0u);
            }
            uint4 rNext = px16[sN];
            int sNN = (k0 + 32 + g < dg) ? sbuf[base + k0 + 32 + g] : sN;
            int j = 0;
            for (; j + 1 < cc; j += 2) {
                uint4 A = sepk[grp][j];
                uint4 B = sepk[grp][j + 1];
                float a = fmaf(__uint_as_float(A.z), w1c8, pre);
                a = __builtin_amdgcn_fdot2(u2h(A.x), wh45, a, false);
                a = __builtin_amdgcn_fdot2(u2h(A.y), wh67, a, false);
                sumH += a * __builtin_amdgcn_rcpf(1.0f + __expf(-a));
                float bb = fmaf(__uint_as_float(B.z), w1c8, pre);
                bb = __builtin_amdgcn_fdot2(u2h(B.x), wh45, bb, false);
                bb = __builtin_amdgcn_fdot2(u2h(B.y), wh67, bb, false);
                sumH += bb * __builtin_amdgcn_rcpf(1.0f + __expf(-bb));
            }
            if (j < cc) {
                uint4 A = sepk[grp][j];
                float a = fmaf(__uint_as_float(A.z), w1c8, pre);
                a = __builtin_amdgcn_fdot2(u2h(A.x), wh45, a, false);
                a = __builtin_amdgcn_fdot2(u2h(A.y), wh67, a, false);
                sumH += a * __builtin_amdgcn_rcpf(1.0f + __expf(-a));
            }
            rC = rNext;
            sN = sNN;
        }

        // LDS-transpose epilogue: lane g applies W2 column g
        smh[grp][g] = sumH;
        float4 s0v = *(const float4*)&smh[grp][0];
        float4 s1v = *(const float4*)&smh[grp][4];
        float4 s2v = *(const float4*)&smh[grp][8];
        float4 s3v = *(const float4*)&smh[grp][12];
        float red = s0v.x * w2col[0] + s0v.y * w2col[1] + s0v.z * w2col[2] + s0v.w * w2col[3]
                  + s1v.x * w2col[4] + s1v.y * w2col[5] + s1v.z * w2col[6] + s1v.w * w2col[7]
                  + s2v.x * w2col[8] + s2v.y * w2col[9] + s2v.z * w2col[10] + s2v.w * w2col[11]
                  + s3v.x * w2col[12] + s3v.y * w2col[13] + s3v.z * w2col[14] + s3v.w * w2col[15];

        float fdg = (float)dg;
        float inv = 1.0f / fmaxf(fdg, 1.0f);
        float h = fmaxf((red + fdg * b2g) * inv, 0.0f);

        float c0 = h * wp0, c1 = h * wp1;
        #pragma unroll
        for (int mset = 8; mset > 0; mset >>= 1) {
            c0 += __shfl_xor(c0, mset);
            c1 += __shfl_xor(c1, mset);
        }
        float l0 = c0 + bp[0], l1 = c1 + bp[1];
        float mx = fmaxf(l0, l1);
        float e0s = __expf(l0 - mx), e1s = __expf(l1 - mx);
        float isum = 1.0f / (e0s + e1s);
        float s0 = e0s * isum, s1 = e1s * isum;

        if (g == 0) ((float2*)out_s)[n] = make_float2(s0, s1);

        int gid = bloc[w];
        int idx = gid - sg0;
        float p0 = s0 * h, p1 = s1 * h;
        if (idx < 4) {
            atomicAdd(&lpool[idx][g], p0);
            atomicAdd(&lpool[idx][16 + g], p1);
        } else {  // pathological many-tiny-graphs fallback
            atomicAdd(&pooled[gid * 32 + g], p0);
            atomicAdd(&pooled[gid * 32 + 16 + g], p1);
        }
    }
    __syncthreads();

    // flush sub-bucket pooling rows
    if (t < 128) {
        int gi = t >> 5, c = t & 31;
        int ngr = bloc[127] - sg0 + 1;
        if (gi < ngr && gi < 4) {
            float v = lpool[gi][c];
            if (v != 0.0f) atomicAdd(&pooled[(sg0 + gi) * 32 + c], v);
        }
    }
}

// ---------------------------------------------------------------------------
// z = pooled.reshape(G,32) @ Wz + bz
// ---------------------------------------------------------------------------
__global__ __launch_bounds__(256) void z_kernel(const float* __restrict__ pooled,
                                                const float* __restrict__ Wz,
                                                const float* __restrict__ bz,
                                                float* __restrict__ out_z) {
    int idx = blockIdx.x * 256 + threadIdx.x;
    if (idx >= N_GRAPHS * 8) return;
    int gph = idx >> 3, o = idx & 7;
    float a = bz[o];
    const float* pp = pooled + (size_t)gph * 32;
    #pragma unroll
    for (int j = 0; j < 32; ++j) a = fmaf(pp[j], Wz[j * 8 + o], a);
    out_z[idx] = a;
}

extern "C" void kernel_launch(void* const* d_in, const int* in_sizes, int n_in,
                              void* d_out, int out_size, void* d_ws, size_t ws_size,
                              hipStream_t stream) {
    const float* x    = (const float*)d_in[0];
    const float* pos  = (const float*)d_in[1];
    const float* W1   = (const float*)d_in[2];
    const float* b1   = (const float*)d_in[3];
    const float* W2   = (const float*)d_in[4];
    const float* b2   = (const float*)d_in[5];
    const float* Wp   = (const float*)d_in[6];
    const float* bp   = (const float*)d_in[7];
    const float* Wz   = (const float*)d_in[8];
    const float* bz   = (const float*)d_in[9];
    const int*   ei   = (const int*)d_in[10];
    const int*   batch= (const int*)d_in[11];
    float* out = (float*)d_out;
    float* out_z = out;                   // [1024*8]
    float* out_s = out + N_GRAPHS * 8;    // [262144*2]

    // ws (ints): gcur[NBK*16] | binned[NBK*CAP] | pooled[1025*32] | px16[N uint4]
    int* gcur     = (int*)d_ws;
    int* binned   = gcur + NBK * 16;
    float* pooled = (float*)(binned + (size_t)NBK * CAP);
    uint4* px16   = (uint4*)(pooled + 1025 * 32);          // 16B-aligned

    hipMemsetAsync(gcur, 0, NBK * 16 * sizeof(int), stream);
    fusedAB<<<ABLK, 256, 0, stream>>>(ei, x, pos, gcur, binned, px16, pooled);
    bucket_fused<<<NBK * 4, 256, 0, stream>>>(gcur, binned, px16, W1, b1, W2, b2,
                                              Wp, bp, batch, out_s, pooled);
    z_kernel<<<32, 256, 0, stream>>>(pooled, Wz, bz, out_z);
}